// Round 5
// baseline (1594.239 us; speedup 1.0000x reference)
//
#include <hip/hip_runtime.h>

#define N_NODES 50000
#define E_EDGES 800000
#define BN 32          // nodes per edge-kernel block (aligned: 50000 % 32 = 16 tail ok)
#define CH 64          // staged edge chunk

// ============================ CSR build =====================================
__global__ __launch_bounds__(256) void k_hist(
    const int* __restrict__ ei, int* __restrict__ cnt)
{
    const int e = blockIdx.x * 256 + threadIdx.x;
    if (e < E_EDGES) atomicAdd(&cnt[ei[E_EDGES + e]], 1);
}

__global__ __launch_bounds__(1024) void k_scan(
    const int* __restrict__ cnt, int* __restrict__ rowptr, int* __restrict__ cursor)
{
    __shared__ int part[1024];
    const int tid = threadIdx.x;
    const int CHS = 49;                      // 1024*49 >= 50000
    const int base = tid * CHS;
    int sum = 0;
    for (int c = 0; c < CHS; ++c) {
        const int i = base + c;
        if (i < N_NODES) sum += cnt[i];
    }
    part[tid] = sum;
    __syncthreads();
    for (int off = 1; off < 1024; off <<= 1) {
        int v = part[tid];
        int u = (tid >= off) ? part[tid - off] : 0;
        __syncthreads();
        part[tid] = v + u;
        __syncthreads();
    }
    int run = (tid > 0) ? part[tid - 1] : 0;
    for (int c = 0; c < CHS; ++c) {
        const int i = base + c;
        if (i < N_NODES) {
            rowptr[i] = run;
            cursor[i] = run;
            run += cnt[i];
        }
    }
    if (tid == 1023) rowptr[N_NODES] = part[1023];
}

// pairs.x = src | (dst % BN) << 16  (src < 65536 fits 16 bits; row fits 5 bits)
__global__ __launch_bounds__(256) void k_scatter(
    const int* __restrict__ ei, int* __restrict__ cursor, int2* __restrict__ pairs)
{
    const int e = blockIdx.x * 256 + threadIdx.x;
    if (e < E_EDGES) {
        const int dst = ei[E_EDGES + e];
        const int pos = atomicAdd(&cursor[dst], 1);
        pairs[pos] = make_int2(ei[e] | ((dst & (BN - 1)) << 16), e);
    }
}

// ===================== Edge layer 1 (16->64) ================================
// Block owns BN nodes (contiguous CSR edge range). Per 64-edge chunk:
//  stage ew-prescaled eattr + packed (src|row) into LDS with coalesced VECTOR
//  loads (no SMEM on the streaming path — round-4 lesson). Consume: lane=dim,
//  ea broadcast via uniform-addr ds_read_b128 (VGPR), h-row gather coalesced,
//  fire-and-forget ds_add into LDS acc (bank lane%32: 2-way = free).
__global__ __launch_bounds__(256) void k_edge1(
    const int* __restrict__ rp, const int2* __restrict__ pairs,
    const float* __restrict__ eattr, const float* __restrict__ ew,
    const float* __restrict__ We1, const float* __restrict__ be1,
    const float* __restrict__ x, float* __restrict__ out)
{
    __shared__ float acc[BN * 64];       // 8 KB
    __shared__ float eaS[CH * 16];       // 4 KB
    __shared__ int   pkS[CH];

    const int tid  = threadIdx.x;
    const int lane = tid & 63;
    const int wv   = tid >> 6;
    const int node0 = blockIdx.x * BN;
    const int nloc  = (N_NODES - node0 < BN) ? (N_NODES - node0) : BN;

    for (int i = tid; i < BN * 64; i += 256) acc[i] = 0.f;

    float wr[16];
#pragma unroll
    for (int k = 0; k < 16; ++k) wr[k] = We1[lane * 16 + k];
    const float bias = be1[lane];
    __syncthreads();

    const int beg = rp[node0], end = rp[node0 + nloc];
    for (int c0 = beg; c0 < end; c0 += CH) {
        const int cn = (end - c0 < CH) ? (end - c0) : CH;
        {   // stage: thread (j=tid>>2, q=tid&3)
            const int j = tid >> 2, q = tid & 3;
            if (j < cn) {
                const int2 sp = pairs[c0 + j];
                const float w = ew[sp.y];
                float4 v = ((const float4*)eattr)[sp.y * 4 + q];
                v.x *= w; v.y *= w; v.z *= w; v.w *= w;
                ((float4*)eaS)[j * 4 + q] = v;
                if (q == 0) pkS[j] = sp.x;
            }
        }
        __syncthreads();

        const int lo = (cn * wv) >> 2, hi = (cn * (wv + 1)) >> 2;
#pragma unroll 2
        for (int j = lo; j < hi; ++j) {
            const int p = __builtin_amdgcn_readfirstlane(pkS[j]);
            const int src = p & 0xFFFF;
            const int row = p >> 16;
            const float4 a0 = ((const float4*)eaS)[j * 4 + 0];
            const float4 a1 = ((const float4*)eaS)[j * 4 + 1];
            const float4 a2 = ((const float4*)eaS)[j * 4 + 2];
            const float4 a3 = ((const float4*)eaS)[j * 4 + 3];
            const float hv = x[(size_t)src * 64 + lane];
            float d0 = fmaf(a0.x, wr[0], a0.y * wr[1]);
            float d1 = fmaf(a0.z, wr[2], a0.w * wr[3]);
            float d2 = fmaf(a1.x, wr[4], a1.y * wr[5]);
            float d3 = fmaf(a1.z, wr[6], a1.w * wr[7]);
            float d4 = fmaf(a2.x, wr[8], a2.y * wr[9]);
            float d5 = fmaf(a2.z, wr[10], a2.w * wr[11]);
            float d6 = fmaf(a3.x, wr[12], a3.y * wr[13]);
            float d7 = fmaf(a3.z, wr[14], a3.w * wr[15]);
            const float dot = ((d0 + d1) + (d2 + d3)) + ((d4 + d5) + (d6 + d7));
            const float m = fmaxf(hv + dot + bias, 0.f);
            atomicAdd(&acc[row * 64 + lane], m);
        }
        __syncthreads();
    }

    for (int i = tid; i < nloc * 16; i += 256) {
        const int n  = i >> 4;
        const int d4 = (i & 15) * 4;
        const size_t g = (size_t)(node0 + n) * 64 + d4;
        const float4 a = *(const float4*)(acc + n * 64 + d4);
        const float4 s = *(const float4*)(x + g);
        *(float4*)(out + g) = make_float4(s.x + a.x, s.y + a.y, s.z + a.z, s.w + a.w);
    }
}

// ===================== Edge layer 2 (16->128) ===============================
// Lane owns dims (2*lane, 2*lane+1): h gather is one dwordx2 (512 B/wave).
__global__ __launch_bounds__(256) void k_edge2(
    const int* __restrict__ rp, const int2* __restrict__ pairs,
    const float* __restrict__ eattr, const float* __restrict__ ew,
    const float* __restrict__ We2, const float* __restrict__ be2,
    const float* __restrict__ h, float* __restrict__ out)
{
    __shared__ float acc[BN * 128];      // 16 KB
    __shared__ float eaS[CH * 16];       // 4 KB
    __shared__ int   pkS[CH];

    const int tid  = threadIdx.x;
    const int lane = tid & 63;
    const int wv   = tid >> 6;
    const int node0 = blockIdx.x * BN;
    const int nloc  = (N_NODES - node0 < BN) ? (N_NODES - node0) : BN;

    for (int i = tid; i < BN * 128; i += 256) acc[i] = 0.f;

    const int dA = 2 * lane, dB = 2 * lane + 1;
    float wrA[16], wrB[16];
#pragma unroll
    for (int k = 0; k < 16; ++k) wrA[k] = We2[dA * 16 + k];
#pragma unroll
    for (int k = 0; k < 16; ++k) wrB[k] = We2[dB * 16 + k];
    const float biasA = be2[dA];
    const float biasB = be2[dB];
    __syncthreads();

    const int beg = rp[node0], end = rp[node0 + nloc];
    for (int c0 = beg; c0 < end; c0 += CH) {
        const int cn = (end - c0 < CH) ? (end - c0) : CH;
        {
            const int j = tid >> 2, q = tid & 3;
            if (j < cn) {
                const int2 sp = pairs[c0 + j];
                const float w = ew[sp.y];
                float4 v = ((const float4*)eattr)[sp.y * 4 + q];
                v.x *= w; v.y *= w; v.z *= w; v.w *= w;
                ((float4*)eaS)[j * 4 + q] = v;
                if (q == 0) pkS[j] = sp.x;
            }
        }
        __syncthreads();

        const int lo = (cn * wv) >> 2, hi = (cn * (wv + 1)) >> 2;
#pragma unroll 2
        for (int j = lo; j < hi; ++j) {
            const int p = __builtin_amdgcn_readfirstlane(pkS[j]);
            const int src = p & 0xFFFF;
            const int row = p >> 16;
            const float4 a0 = ((const float4*)eaS)[j * 4 + 0];
            const float4 a1 = ((const float4*)eaS)[j * 4 + 1];
            const float4 a2 = ((const float4*)eaS)[j * 4 + 2];
            const float4 a3 = ((const float4*)eaS)[j * 4 + 3];
            const float2 hv = *(const float2*)(h + (size_t)src * 128 + dA);
            float p0 = fmaf(a0.x, wrA[0], a0.y * wrA[1]);
            float p1 = fmaf(a0.z, wrA[2], a0.w * wrA[3]);
            float p2 = fmaf(a1.x, wrA[4], a1.y * wrA[5]);
            float p3 = fmaf(a1.z, wrA[6], a1.w * wrA[7]);
            float p4 = fmaf(a2.x, wrA[8], a2.y * wrA[9]);
            float p5 = fmaf(a2.z, wrA[10], a2.w * wrA[11]);
            float p6 = fmaf(a3.x, wrA[12], a3.y * wrA[13]);
            float p7 = fmaf(a3.z, wrA[14], a3.w * wrA[15]);
            const float dotA = ((p0 + p1) + (p2 + p3)) + ((p4 + p5) + (p6 + p7));
            float q0 = fmaf(a0.x, wrB[0], a0.y * wrB[1]);
            float q1 = fmaf(a0.z, wrB[2], a0.w * wrB[3]);
            float q2 = fmaf(a1.x, wrB[4], a1.y * wrB[5]);
            float q3 = fmaf(a1.z, wrB[6], a1.w * wrB[7]);
            float q4 = fmaf(a2.x, wrB[8], a2.y * wrB[9]);
            float q5 = fmaf(a2.z, wrB[10], a2.w * wrB[11]);
            float q6 = fmaf(a3.x, wrB[12], a3.y * wrB[13]);
            float q7 = fmaf(a3.z, wrB[14], a3.w * wrB[15]);
            const float dotB = ((q0 + q1) + (q2 + q3)) + ((q4 + q5) + (q6 + q7));
            atomicAdd(&acc[row * 128 + dA], fmaxf(hv.x + dotA + biasA, 0.f));
            atomicAdd(&acc[row * 128 + dB], fmaxf(hv.y + dotB + biasB, 0.f));
        }
        __syncthreads();
    }

    for (int i = tid; i < nloc * 32; i += 256) {
        const int n  = i >> 5;
        const int d4 = (i & 31) * 4;
        const size_t g = (size_t)(node0 + n) * 128 + d4;
        const float4 a = *(const float4*)(acc + n * 128 + d4);
        const float4 s = *(const float4*)(h + g);
        *(float4*)(out + g) = make_float4(s.x + a.x, s.y + a.y, s.z + a.z, s.w + a.w);
    }
}

// ========================= Dense GEMM (node MLP) ============================
// Round-3 known configuration (256 threads).
#define NT 128

template<int KIN, int JOUT, bool RELU>
__global__ __launch_bounds__(256) void k_mlp(
    const float* __restrict__ H, const float* __restrict__ W,
    const float* __restrict__ b, float* __restrict__ OUT)
{
    extern __shared__ float lds[];
    float* Wt = lds;                       // [KIN][128]
    float* hN = Wt + KIN * 128;            // [NT][KIN+4]
    const int HS = KIN + 4;

    const int tid  = threadIdx.x;
    const int nq   = tid & 7;
    const int jq   = (tid >> 3) & 15;
    const int half = tid >> 7;
    const int j0   = jq * 8;

    for (int idx = tid; idx < 128 * KIN; idx += 256) {
        const int j = idx / KIN, k = idx % KIN;
        Wt[k * 128 + j] = (j < JOUT) ? W[idx] : 0.f;
    }
    float bj[8];
#pragma unroll
    for (int m = 0; m < 8; ++m)
        bj[m] = (j0 + m < JOUT) ? b[j0 + m] : 0.f;
    __syncthreads();

    const int base = blockIdx.x * NT;

    for (int idx = tid; idx < NT * (KIN / 4); idx += 256) {
        const int kq = idx & (KIN / 4 - 1);
        const int n  = idx / (KIN / 4);
        const int ng = (base + n < N_NODES) ? (base + n) : (N_NODES - 1);
        *(float4*)(hN + n * HS + 4 * kq) =
            *(const float4*)(H + (size_t)ng * KIN + 4 * kq);
    }
    __syncthreads();

    int hoff[8];
#pragma unroll
    for (int i = 0; i < 8; ++i)
        hoff[i] = (64 * half + nq + 8 * i) * HS;

    float acc[8][8];
#pragma unroll
    for (int i = 0; i < 8; ++i)
#pragma unroll
        for (int m = 0; m < 8; ++m) acc[i][m] = 0.f;

#pragma unroll 4
    for (int k = 0; k < KIN; ++k) {
        const float4 wA = *(const float4*)(Wt + k * 128 + j0);
        const float4 wB = *(const float4*)(Wt + k * 128 + j0 + 4);
        float hv[8];
#pragma unroll
        for (int i = 0; i < 8; ++i) hv[i] = hN[hoff[i] + k];
#pragma unroll
        for (int i = 0; i < 8; ++i) {
            acc[i][0] = fmaf(hv[i], wA.x, acc[i][0]);
            acc[i][1] = fmaf(hv[i], wA.y, acc[i][1]);
            acc[i][2] = fmaf(hv[i], wA.z, acc[i][2]);
            acc[i][3] = fmaf(hv[i], wA.w, acc[i][3]);
            acc[i][4] = fmaf(hv[i], wB.x, acc[i][4]);
            acc[i][5] = fmaf(hv[i], wB.y, acc[i][5]);
            acc[i][6] = fmaf(hv[i], wB.z, acc[i][6]);
            acc[i][7] = fmaf(hv[i], wB.w, acc[i][7]);
        }
    }

#pragma unroll
    for (int i = 0; i < 8; ++i) {
        const int n = base + 64 * half + nq + 8 * i;
        if (n >= N_NODES) continue;
        float v[8];
#pragma unroll
        for (int m = 0; m < 8; ++m) {
            float t = acc[i][m] + bj[m];
            v[m] = RELU ? fmaxf(t, 0.f) : t;
        }
        float* row = OUT + (size_t)n * JOUT;
        if (JOUT == 128) {
            *(float4*)(row + j0)     = make_float4(v[0], v[1], v[2], v[3]);
            *(float4*)(row + j0 + 4) = make_float4(v[4], v[5], v[6], v[7]);
        } else {
#pragma unroll
            for (int m = 0; m < 8; ++m)
                if (j0 + m < JOUT) row[j0 + m] = v[m];
        }
    }
}

// ============================================================================
extern "C" void kernel_launch(void* const* d_in, const int* in_sizes, int n_in,
                              void* d_out, int out_size, void* d_ws, size_t ws_size,
                              hipStream_t stream) {
    const float* x     = (const float*)d_in[0];
    const int*   ei    = (const int*)  d_in[1];
    const float* eattr = (const float*)d_in[2];
    const float* ew    = (const float*)d_in[3];
    const float* We1   = (const float*)d_in[4];
    const float* be1   = (const float*)d_in[5];
    const float* W11   = (const float*)d_in[6];
    const float* b11   = (const float*)d_in[7];
    const float* W12   = (const float*)d_in[8];
    const float* b12   = (const float*)d_in[9];
    const float* We2   = (const float*)d_in[10];
    const float* be2   = (const float*)d_in[11];
    const float* W21   = (const float*)d_in[12];
    const float* b21   = (const float*)d_in[13];
    const float* W22   = (const float*)d_in[14];
    const float* b22   = (const float*)d_in[15];
    const float* Wo    = (const float*)d_in[16];
    const float* bo    = (const float*)d_in[17];
    float* out = (float*)d_out;

    // Buffer liveness (A=12.8M, B=25.6M, C=25.6M):
    //   edge1: x -> A | mlp: A -> B | mlp: B -> C | edge2: C -> B
    //   mlp: B -> C | mlp: C -> B | head: B -> out     (total 71.0 MB, as r2-4)
    char* ws = (char*)d_ws;
    int*  cnt    = (int*)(ws + 0);            // 200,000 B
    int*  rowptr = (int*)(ws + 204800);       // 200,004 B
    int*  cursor = (int*)(ws + 409600);       // 200,000 B
    int2* pairs  = (int2*)(ws + 614400);      // 6,400,000 B
    float* A = (float*)(ws + 7014400);        // 12.8 MB
    float* B = (float*)(ws + 19814400);       // 25.6 MB
    float* C = (float*)(ws + 45414400);       // 25.6 MB

    hipMemsetAsync(cnt, 0, 200000, stream);

    const int EB = (E_EDGES + 255) / 256;     // 3125
    k_hist<<<EB, 256, 0, stream>>>(ei, cnt);
    k_scan<<<1, 1024, 0, stream>>>(cnt, rowptr, cursor);
    k_scatter<<<EB, 256, 0, stream>>>(ei, cursor, pairs);

    const int NBE = (N_NODES + BN - 1) / BN;  // 1563
    k_edge1<<<NBE, 256, 0, stream>>>(rowptr, pairs, eattr, ew, We1, be1, x, A);

    const int TILES = (N_NODES + NT - 1) / NT;                       // 391
    const size_t lds64  = (size_t)(64 * 128 + NT * (64 + 4)) * 4;    //  67,584 B
    const size_t lds128 = (size_t)(128 * 128 + NT * (128 + 4)) * 4;  // 133,120 B

    k_mlp<64, 128, true><<<TILES, 256, lds64, stream>>>(A, W11, b11, B);
    k_mlp<128, 128, true><<<TILES, 256, lds128, stream>>>(B, W12, b12, C);

    k_edge2<<<NBE, 256, 0, stream>>>(rowptr, pairs, eattr, ew, We2, be2, C, B);

    k_mlp<128, 128, true><<<TILES, 256, lds128, stream>>>(B, W21, b21, C);
    k_mlp<128, 128, true><<<TILES, 256, lds128, stream>>>(C, W22, b22, B);
    k_mlp<128, 100, false><<<TILES, 256, lds128, stream>>>(B, Wo, bo, out);
}

// Round 6
// 1524.832 us; speedup vs baseline: 1.0455x; 1.0455x over previous
//
#include <hip/hip_runtime.h>

#define N_NODES 50000
#define E_EDGES 800000
#define EB   512      // edges per edge-kernel block
#define ROWS 64       // LDS accumulator rows (span of 512 CSR edges ~32+-6)

// ============================ CSR build =====================================
__global__ __launch_bounds__(256) void k_hist(
    const int* __restrict__ ei, int* __restrict__ cnt)
{
    const int e = blockIdx.x * 256 + threadIdx.x;
    if (e < E_EDGES) atomicAdd(&cnt[ei[E_EDGES + e]], 1);
}

// single block, 1024 threads: exclusive prefix over cnt -> cursor
__global__ __launch_bounds__(1024) void k_scan(
    const int* __restrict__ cnt, int* __restrict__ cursor)
{
    __shared__ int part[1024];
    const int tid = threadIdx.x;
    const int CHS = 49;                      // 1024*49 >= 50000
    const int base = tid * CHS;
    int sum = 0;
    for (int c = 0; c < CHS; ++c) {
        const int i = base + c;
        if (i < N_NODES) sum += cnt[i];
    }
    part[tid] = sum;
    __syncthreads();
    for (int off = 1; off < 1024; off <<= 1) {
        int v = part[tid];
        int u = (tid >= off) ? part[tid - off] : 0;
        __syncthreads();
        part[tid] = v + u;
        __syncthreads();
    }
    int run = (tid > 0) ? part[tid - 1] : 0;
    for (int c = 0; c < CHS; ++c) {
        const int i = base + c;
        if (i < N_NODES) {
            cursor[i] = run;
            run += cnt[i];
        }
    }
}

// Permute edges into CSR-by-dst order: sd[pos] = src | dst<<16 (uint),
// eaP[pos] = eattr[e] * ew[e] (16 floats). Consumers then stream
// sd/eaP sequentially — no indirection in the hot loops.
__global__ __launch_bounds__(256) void k_scatter(
    const int* __restrict__ ei, const float* __restrict__ eattr,
    const float* __restrict__ ew, int* __restrict__ cursor,
    unsigned* __restrict__ sd, float* __restrict__ eaP)
{
    const int e = blockIdx.x * 256 + threadIdx.x;
    if (e < E_EDGES) {
        const int src = ei[e];
        const int dst = ei[E_EDGES + e];
        const int pos = atomicAdd(&cursor[dst], 1);
        sd[pos] = (unsigned)src | ((unsigned)dst << 16);
        const float w = ew[e];
        const float4* s4 = (const float4*)(eattr + (size_t)e * 16);
        float4* d4 = (float4*)(eaP + (size_t)pos * 16);
#pragma unroll
        for (int q = 0; q < 4; ++q) {
            float4 v = s4[q];
            v.x *= w; v.y *= w; v.z *= w; v.w *= w;
            d4[q] = v;
        }
    }
}

// ===================== Edge layer 1 (16->64) ================================
// Block owns edges [b*EB, b*EB+EB) (CSR-sorted by dst). Wave per edge,
// lane = dim. ALL loads vector-path (broadcast or coalesced), all addresses
// VGPR — no readfirstlane, no SMEM streaming (rounds 4-5 lesson). Messages
// ds_add into LDS rows (dst - dst_min); flush: interior rows plain RMW
// (exclusively owned), boundary rows atomicAdd. out pre-filled with x.
__global__ __launch_bounds__(256) void k_edge1(
    const unsigned* __restrict__ sd, const float* __restrict__ eaP,
    const float* __restrict__ We1, const float* __restrict__ be1,
    const float* __restrict__ x, float* __restrict__ out)
{
    __shared__ float acc[ROWS * 64];        // 16 KB
    const int tid  = threadIdx.x;
    const int lane = tid & 63;
    const int wv   = tid >> 6;
    const int r0 = blockIdx.x * EB;
    const int r1 = (E_EDGES - r0 < EB) ? E_EDGES : r0 + EB;

    for (int i = tid; i < ROWS * 64; i += 256) acc[i] = 0.f;

    float wr[16];
#pragma unroll
    for (int k = 0; k < 16; ++k) wr[k] = We1[lane * 16 + k];
    const float bias = be1[lane];
    const int dst_min = (int)(sd[r0] >> 16);     // broadcast load, stays VGPR
    __syncthreads();

#pragma unroll 4
    for (int e = r0 + wv; e < r1; e += 4) {
        const unsigned p = sd[e];                // broadcast
        const float4* ea = (const float4*)(eaP + (size_t)e * 16);
        const float4 a0 = ea[0], a1 = ea[1], a2 = ea[2], a3 = ea[3];
        const int src = (int)(p & 0xFFFFu);
        const int row = (int)(p >> 16) - dst_min;
        const float hv = x[src * 64 + lane];     // coalesced row gather
        float d0 = fmaf(a0.x, wr[0], a0.y * wr[1]);
        float d1 = fmaf(a0.z, wr[2], a0.w * wr[3]);
        float d2 = fmaf(a1.x, wr[4], a1.y * wr[5]);
        float d3 = fmaf(a1.z, wr[6], a1.w * wr[7]);
        float d4 = fmaf(a2.x, wr[8], a2.y * wr[9]);
        float d5 = fmaf(a2.z, wr[10], a2.w * wr[11]);
        float d6 = fmaf(a3.x, wr[12], a3.y * wr[13]);
        float d7 = fmaf(a3.z, wr[14], a3.w * wr[15]);
        const float dot = ((d0 + d1) + (d2 + d3)) + ((d4 + d5) + (d6 + d7));
        const float m = fmaxf(hv + dot + bias, 0.f);
        if (row < ROWS) {
            atomicAdd(&acc[row * 64 + lane], m);         // ds_add, no dep
        } else {                                         // ~never (5+ sigma)
            atomicAdd(&out[((size_t)dst_min + row) * 64 + lane], m);
        }
    }
    __syncthreads();

    const int dst_last = (int)(sd[r1 - 1] >> 16);
    int span = dst_last - dst_min + 1;
    if (span > ROWS) span = ROWS;
    for (int i = tid; i < span * 16; i += 256) {
        const int n  = i >> 4;
        const int d4 = (i & 15) * 4;
        const float4 a = *(const float4*)(acc + n * 64 + d4);
        float* g = out + ((size_t)dst_min + n) * 64 + d4;
        if (n == 0 || n == span - 1) {          // shared with adjacent block
            atomicAdd(g + 0, a.x); atomicAdd(g + 1, a.y);
            atomicAdd(g + 2, a.z); atomicAdd(g + 3, a.w);
        } else {                                 // exclusively owned
            const float4 c = *(const float4*)g;
            *(float4*)g = make_float4(c.x + a.x, c.y + a.y, c.z + a.z, c.w + a.w);
        }
    }
}

// ===================== Edge layer 2 (16->128) ===============================
// Lane owns dims (2*lane, 2*lane+1): h gather one dwordx2 (512 B/wave/edge).
__global__ __launch_bounds__(256) void k_edge2(
    const unsigned* __restrict__ sd, const float* __restrict__ eaP,
    const float* __restrict__ We2, const float* __restrict__ be2,
    const float* __restrict__ h, float* __restrict__ out)
{
    __shared__ float acc[ROWS * 128];       // 32 KB
    const int tid  = threadIdx.x;
    const int lane = tid & 63;
    const int wv   = tid >> 6;
    const int r0 = blockIdx.x * EB;
    const int r1 = (E_EDGES - r0 < EB) ? E_EDGES : r0 + EB;

    for (int i = tid; i < ROWS * 128; i += 256) acc[i] = 0.f;

    const int dA = 2 * lane;
    float wrA[16], wrB[16];
#pragma unroll
    for (int k = 0; k < 16; ++k) wrA[k] = We2[dA * 16 + k];
#pragma unroll
    for (int k = 0; k < 16; ++k) wrB[k] = We2[(dA + 1) * 16 + k];
    const float biasA = be2[dA];
    const float biasB = be2[dA + 1];
    const int dst_min = (int)(sd[r0] >> 16);
    __syncthreads();

#pragma unroll 2
    for (int e = r0 + wv; e < r1; e += 4) {
        const unsigned p = sd[e];
        const float4* ea = (const float4*)(eaP + (size_t)e * 16);
        const float4 a0 = ea[0], a1 = ea[1], a2 = ea[2], a3 = ea[3];
        const int src = (int)(p & 0xFFFFu);
        const int row = (int)(p >> 16) - dst_min;
        const float2 hv = *(const float2*)(h + src * 128 + dA);
        float p0 = fmaf(a0.x, wrA[0], a0.y * wrA[1]);
        float p1 = fmaf(a0.z, wrA[2], a0.w * wrA[3]);
        float p2 = fmaf(a1.x, wrA[4], a1.y * wrA[5]);
        float p3 = fmaf(a1.z, wrA[6], a1.w * wrA[7]);
        float p4 = fmaf(a2.x, wrA[8], a2.y * wrA[9]);
        float p5 = fmaf(a2.z, wrA[10], a2.w * wrA[11]);
        float p6 = fmaf(a3.x, wrA[12], a3.y * wrA[13]);
        float p7 = fmaf(a3.z, wrA[14], a3.w * wrA[15]);
        const float dotA = ((p0 + p1) + (p2 + p3)) + ((p4 + p5) + (p6 + p7));
        float q0 = fmaf(a0.x, wrB[0], a0.y * wrB[1]);
        float q1 = fmaf(a0.z, wrB[2], a0.w * wrB[3]);
        float q2 = fmaf(a1.x, wrB[4], a1.y * wrB[5]);
        float q3 = fmaf(a1.z, wrB[6], a1.w * wrB[7]);
        float q4 = fmaf(a2.x, wrB[8], a2.y * wrB[9]);
        float q5 = fmaf(a2.z, wrB[10], a2.w * wrB[11]);
        float q6 = fmaf(a3.x, wrB[12], a3.y * wrB[13]);
        float q7 = fmaf(a3.z, wrB[14], a3.w * wrB[15]);
        const float dotB = ((q0 + q1) + (q2 + q3)) + ((q4 + q5) + (q6 + q7));
        const float mA = fmaxf(hv.x + dotA + biasA, 0.f);
        const float mB = fmaxf(hv.y + dotB + biasB, 0.f);
        if (row < ROWS) {
            atomicAdd(&acc[row * 128 + dA],     mA);
            atomicAdd(&acc[row * 128 + dA + 1], mB);
        } else {
            atomicAdd(&out[((size_t)dst_min + row) * 128 + dA],     mA);
            atomicAdd(&out[((size_t)dst_min + row) * 128 + dA + 1], mB);
        }
    }
    __syncthreads();

    const int dst_last = (int)(sd[r1 - 1] >> 16);
    int span = dst_last - dst_min + 1;
    if (span > ROWS) span = ROWS;
    for (int i = tid; i < span * 32; i += 256) {
        const int n  = i >> 5;
        const int d4 = (i & 31) * 4;
        const float4 a = *(const float4*)(acc + n * 128 + d4);
        float* g = out + ((size_t)dst_min + n) * 128 + d4;
        if (n == 0 || n == span - 1) {
            atomicAdd(g + 0, a.x); atomicAdd(g + 1, a.y);
            atomicAdd(g + 2, a.z); atomicAdd(g + 3, a.w);
        } else {
            const float4 c = *(const float4*)g;
            *(float4*)g = make_float4(c.x + a.x, c.y + a.y, c.z + a.z, c.w + a.w);
        }
    }
}

// ========================= Dense GEMM (node MLP) ============================
#define NT 128

template<int KIN, int JOUT, bool RELU>
__global__ __launch_bounds__(256) void k_mlp(
    const float* __restrict__ H, const float* __restrict__ W,
    const float* __restrict__ b, float* __restrict__ OUT)
{
    extern __shared__ float lds[];
    float* Wt = lds;                       // [KIN][128]
    float* hN = Wt + KIN * 128;            // [NT][KIN+4]
    const int HS = KIN + 4;

    const int tid  = threadIdx.x;
    const int nq   = tid & 7;
    const int jq   = (tid >> 3) & 15;
    const int half = tid >> 7;
    const int j0   = jq * 8;

    for (int idx = tid; idx < 128 * KIN; idx += 256) {
        const int j = idx / KIN, k = idx % KIN;
        Wt[k * 128 + j] = (j < JOUT) ? W[idx] : 0.f;
    }
    float bj[8];
#pragma unroll
    for (int m = 0; m < 8; ++m)
        bj[m] = (j0 + m < JOUT) ? b[j0 + m] : 0.f;
    __syncthreads();

    const int base = blockIdx.x * NT;

    for (int idx = tid; idx < NT * (KIN / 4); idx += 256) {
        const int kq = idx & (KIN / 4 - 1);
        const int n  = idx / (KIN / 4);
        const int ng = (base + n < N_NODES) ? (base + n) : (N_NODES - 1);
        *(float4*)(hN + n * HS + 4 * kq) =
            *(const float4*)(H + (size_t)ng * KIN + 4 * kq);
    }
    __syncthreads();

    int hoff[8];
#pragma unroll
    for (int i = 0; i < 8; ++i)
        hoff[i] = (64 * half + nq + 8 * i) * HS;

    float acc[8][8];
#pragma unroll
    for (int i = 0; i < 8; ++i)
#pragma unroll
        for (int m = 0; m < 8; ++m) acc[i][m] = 0.f;

#pragma unroll 4
    for (int k = 0; k < KIN; ++k) {
        const float4 wA = *(const float4*)(Wt + k * 128 + j0);
        const float4 wB = *(const float4*)(Wt + k * 128 + j0 + 4);
        float hv[8];
#pragma unroll
        for (int i = 0; i < 8; ++i) hv[i] = hN[hoff[i] + k];
#pragma unroll
        for (int i = 0; i < 8; ++i) {
            acc[i][0] = fmaf(hv[i], wA.x, acc[i][0]);
            acc[i][1] = fmaf(hv[i], wA.y, acc[i][1]);
            acc[i][2] = fmaf(hv[i], wA.z, acc[i][2]);
            acc[i][3] = fmaf(hv[i], wA.w, acc[i][3]);
            acc[i][4] = fmaf(hv[i], wB.x, acc[i][4]);
            acc[i][5] = fmaf(hv[i], wB.y, acc[i][5]);
            acc[i][6] = fmaf(hv[i], wB.z, acc[i][6]);
            acc[i][7] = fmaf(hv[i], wB.w, acc[i][7]);
        }
    }

#pragma unroll
    for (int i = 0; i < 8; ++i) {
        const int n = base + 64 * half + nq + 8 * i;
        if (n >= N_NODES) continue;
        float v[8];
#pragma unroll
        for (int m = 0; m < 8; ++m) {
            float t = acc[i][m] + bj[m];
            v[m] = RELU ? fmaxf(t, 0.f) : t;
        }
        float* row = OUT + (size_t)n * JOUT;
        if (JOUT == 128) {
            *(float4*)(row + j0)     = make_float4(v[0], v[1], v[2], v[3]);
            *(float4*)(row + j0 + 4) = make_float4(v[4], v[5], v[6], v[7]);
        } else {
#pragma unroll
            for (int m = 0; m < 8; ++m)
                if (j0 + m < JOUT) row[j0 + m] = v[m];
        }
    }
}

// ============================================================================
extern "C" void kernel_launch(void* const* d_in, const int* in_sizes, int n_in,
                              void* d_out, int out_size, void* d_ws, size_t ws_size,
                              hipStream_t stream) {
    const float* x     = (const float*)d_in[0];
    const int*   ei    = (const int*)  d_in[1];
    const float* eattr = (const float*)d_in[2];
    const float* ew    = (const float*)d_in[3];
    const float* We1   = (const float*)d_in[4];
    const float* be1   = (const float*)d_in[5];
    const float* W11   = (const float*)d_in[6];
    const float* b11   = (const float*)d_in[7];
    const float* W12   = (const float*)d_in[8];
    const float* b12   = (const float*)d_in[9];
    const float* We2   = (const float*)d_in[10];
    const float* be2   = (const float*)d_in[11];
    const float* W21   = (const float*)d_in[12];
    const float* b21   = (const float*)d_in[13];
    const float* W22   = (const float*)d_in[14];
    const float* b22   = (const float*)d_in[15];
    const float* Wo    = (const float*)d_in[16];
    const float* bo    = (const float*)d_in[17];
    float* out = (float*)d_out;

    char* ws = (char*)d_ws;
    int*      cnt    = (int*)     (ws + 0);           //   200,000 B
    int*      cursor = (int*)     (ws + 204800);      //   200,000 B
    unsigned* sd     = (unsigned*)(ws + 409600);      // 3,200,000 B
    float*    eaP    = (float*)   (ws + 3609600);     // 51,200,000 B
    float*    A      = (float*)   (ws + 54809600);    // 12.8 MB
    float*    B      = (float*)   (ws + 67609600);    // 25.6 MB
    float*    C      = (float*)   (ws + 93209600);    // 25.6 MB

    hipMemsetAsync(cnt, 0, 200000, stream);

    const int EBk = (E_EDGES + 255) / 256;    // 3125
    k_hist<<<EBk, 256, 0, stream>>>(ei, cnt);
    k_scan<<<1, 1024, 0, stream>>>(cnt, cursor);
    k_scatter<<<EBk, 256, 0, stream>>>(ei, eattr, ew, cursor, sd, eaP);

    const int GB = (E_EDGES + EB - 1) / EB;   // 1563 edge-range blocks

    // ---- layer 1: A = x + scatter(relu(x[src]+e1)) ; MLP -> C (=h1)
    hipMemcpyAsync(A, x, (size_t)N_NODES * 64 * 4, hipMemcpyDeviceToDevice, stream);
    k_edge1<<<GB, 256, 0, stream>>>(sd, eaP, We1, be1, x, A);

    const int TILES = (N_NODES + NT - 1) / NT;                       // 391
    const size_t lds64  = (size_t)(64 * 128 + NT * (64 + 4)) * 4;    //  67,584 B
    const size_t lds128 = (size_t)(128 * 128 + NT * (128 + 4)) * 4;  // 133,120 B

    k_mlp<64, 128, true><<<TILES, 256, lds64, stream>>>(A, W11, b11, B);
    k_mlp<128, 128, true><<<TILES, 256, lds128, stream>>>(B, W12, b12, C);

    // ---- layer 2: B = h1 + scatter(relu(h1[src]+e2)) ; MLP -> out
    hipMemcpyAsync(B, C, (size_t)N_NODES * 128 * 4, hipMemcpyDeviceToDevice, stream);
    k_edge2<<<GB, 256, 0, stream>>>(sd, eaP, We2, be2, C, B);

    k_mlp<128, 128, true><<<TILES, 256, lds128, stream>>>(B, W21, b21, C);
    k_mlp<128, 128, true><<<TILES, 256, lds128, stream>>>(C, W22, b22, B);
    k_mlp<128, 100, false><<<TILES, 256, lds128, stream>>>(B, Wo, bo, out);
}